// Round 23
// baseline (83.392 us; speedup 1.0000x reference)
//
#include <hip/hip_runtime.h>
#include <cstddef>
#include <cstdint>

// ---------------- problem constants ----------------
#define B_     2
#define NSEQ   2048
#define C_     512
#define H_     8
#define D_     64
#define NFULL  (NSEQ * C_)        // 1048576 elems per batch
#define N4     (NFULL / 4)        // 262144 float4 per batch
#define EPS_   1e-5f
#define LOG2E  1.4426950408889634f
#define RSQRT512 0.044194173824159216f
#define ASCL   (RSQRT512 * LOG2E)
#define NBLK_RED 256

typedef __attribute__((ext_vector_type(8)))  short bf16x8;
typedef __attribute__((ext_vector_type(4)))  float f32x4;
typedef __attribute__((ext_vector_type(16))) float f32x16;
typedef __attribute__((ext_vector_type(4)))  unsigned int u32x4;

__device__ __forceinline__ unsigned short f2b(float x) {
    unsigned int u = __float_as_uint(x);
    u += 0x7FFFu + ((u >> 16) & 1u);          // RNE
    return (unsigned short)(u >> 16);
}
__device__ __forceinline__ float b2f(unsigned short h) {
    return __uint_as_float(((unsigned int)h) << 16);
}

// ---------------- setup: weight prep (blocks 0..255) + set-norm partial stats (256..1279) ----------------
__global__ __launch_bounds__(256) void setup_k(const float* __restrict__ query,
                                               const float* __restrict__ key_value,
                                               const float* __restrict__ Wq, const float* __restrict__ Wk,
                                               const float* __restrict__ Wv, const float* __restrict__ Wo,
                                               unsigned short* __restrict__ Wt_hi,
                                               float2* __restrict__ part_q,
                                               float2* __restrict__ part_kv)
{
    __shared__ float T[64][65];
    __shared__ float rs[256], rss[256];
    const int bid = blockIdx.x;
    const int tid = threadIdx.x;

    if (bid < 256) {
        int z = bid >> 6;
        const float* W = (z == 0) ? Wq : (z == 1) ? Wk : (z == 2) ? Wv : Wo;
        int k0 = (bid & 7) * 64, n0 = ((bid >> 3) & 7) * 64;
#pragma unroll
        for (int i = 0; i < 4; ++i) {
            int idx = tid + i * 256;
            int r = idx >> 4, c4 = (idx & 15) * 4;
            float4 v = *reinterpret_cast<const float4*>(W + (size_t)(k0 + r) * 512 + n0 + c4);
            T[r][c4] = v.x; T[r][c4 + 1] = v.y; T[r][c4 + 2] = v.z; T[r][c4 + 3] = v.w;
        }
        __syncthreads();
#pragma unroll
        for (int i = 0; i < 4; ++i) {
            int idx = tid + i * 256;
            int n = idx >> 4, k4 = (idx & 15) * 4;
            ushort4 hi;
            hi.x = f2b(T[k4 + 0][n]); hi.y = f2b(T[k4 + 1][n]);
            hi.z = f2b(T[k4 + 2][n]); hi.w = f2b(T[k4 + 3][n]);
            size_t o = ((size_t)z * 512 + n0 + n) * 512 + k0 + k4;
            *reinterpret_cast<ushort4*>(Wt_hi + o) = hi;
        }
    } else {
        int r = bid - 256;
        int zz = r >> 9, bb = (r >> 8) & 1, xx = r & 255;
        const float* x = zz ? key_value : query;
        float2* partials = zz ? part_kv : part_q;
        const float4* xb = reinterpret_cast<const float4*>(x + (size_t)bb * NFULL);
        int base = xx * 1024 + tid;
        float s = 0.f, ss = 0.f;
#pragma unroll
        for (int i = 0; i < 4; ++i) {
            float4 v = xb[base + i * 256];
            s  += (v.x + v.y) + (v.z + v.w);
            ss += (v.x * v.x + v.y * v.y) + (v.z * v.z + v.w * v.w);
        }
        rs[tid] = s; rss[tid] = ss;
        __syncthreads();
        for (int off = 128; off > 0; off >>= 1) {
            if (tid < off) { rs[tid] += rs[tid + off]; rss[tid] += rss[tid + off]; }
            __syncthreads();
        }
        if (tid == 0)
            partials[bb * NBLK_RED + xx] = make_float2(rs[0], rss[0]);
    }
}

// ---------------- QKV projection GEMM with fused set-norm on A (reads fp32 inputs) ----------------
__global__ __launch_bounds__(256) void gemm3_fused_k(const float* __restrict__ query,
                                                     const float* __restrict__ key_value,
                                                     const float2* __restrict__ part_q,
                                                     const float2* __restrict__ part_kv,
                                                     const float* __restrict__ g_q, const float* __restrict__ be_q,
                                                     const float* __restrict__ g_k, const float* __restrict__ be_k,
                                                     const unsigned short* __restrict__ Wt_hi,
                                                     const float* __restrict__ bq, const float* __restrict__ bk,
                                                     const float* __restrict__ bv,
                                                     unsigned short* __restrict__ Qb,
                                                     unsigned short* __restrict__ Kb,
                                                     unsigned short* __restrict__ Vt)
{
    int z = blockIdx.z;
    const float* xin = (z == 0) ? query : key_value;
    const float2* partials = (z == 0) ? part_q : part_kv;
    const float* gamma = (z == 0) ? g_q : g_k;
    const float* beta  = (z == 0) ? be_q : be_k;
    const unsigned short* W = Wt_hi + (size_t)z * 512 * 512;
    const float* bias = (z == 0) ? bq : (z == 1) ? bk : bv;
    float scale = (z == 0) ? (float)ASCL : 1.0f;

    __shared__ unsigned short AH[64][40];
    __shared__ unsigned short BH[128][40];
    __shared__ float rs[256], rss[256];
    __shared__ float2 stt;
    const int tid = threadIdx.x;
    const int w = tid >> 6, lane = tid & 63, l15 = lane & 15, l4 = lane >> 4;
    const int wm = w >> 1, wn = w & 1;
    const int m0 = blockIdx.x * 64, n0 = blockIdx.y * 128;
    const int b = m0 >> 11;

    float2 pp = partials[b * NBLK_RED + tid];
    rs[tid] = pp.x; rss[tid] = pp.y;
    __syncthreads();
    for (int off = 128; off > 0; off >>= 1) {
        if (tid < off) { rs[tid] += rs[tid + off]; rss[tid] += rss[tid + off]; }
        __syncthreads();
    }
    if (tid == 0) {
        float mu  = rs[0] / (float)NFULL;
        float var = rss[0] / (float)NFULL - mu * mu;
        stt = make_float2(mu, rsqrtf(var + EPS_));
    }
    __syncthreads();
    const float2 st = stt;

    f32x4 acc[2][4];
#pragma unroll
    for (int mi = 0; mi < 2; ++mi)
#pragma unroll
        for (int nj = 0; nj < 4; ++nj) acc[mi][nj] = (f32x4){0.f, 0.f, 0.f, 0.f};

    for (int kt = 0; kt < 512; kt += 32) {
#pragma unroll
        for (int p = 0; p < 2; ++p) {   // A tile 64x32 fp32, normalize -> bf16 LDS
            int f = tid + p * 256;
            int r = f >> 3, c4 = (f & 7) * 4;
            float4 v = *reinterpret_cast<const float4*>(xin + (size_t)(m0 + r) * 512 + kt + c4);
            float4 g  = *reinterpret_cast<const float4*>(gamma + kt + c4);
            float4 be = *reinterpret_cast<const float4*>(beta + kt + c4);
            ushort4 hi;
            hi.x = f2b((v.x - st.x) * st.y * g.x + be.x);
            hi.y = f2b((v.y - st.x) * st.y * g.y + be.y);
            hi.z = f2b((v.z - st.x) * st.y * g.z + be.z);
            hi.w = f2b((v.w - st.x) * st.y * g.w + be.w);
            *reinterpret_cast<ushort4*>(&AH[r][c4]) = hi;
        }
#pragma unroll
        for (int p = 0; p < 2; ++p) {   // B tile 128x32 = 512 uint4, 2/thread
            int f = tid + p * 256;
            int r = f >> 2, c8 = (f & 3) * 8;
            *reinterpret_cast<uint4*>(&BH[r][c8]) =
                *reinterpret_cast<const uint4*>(W + (size_t)(n0 + r) * 512 + kt + c8);
        }
        __syncthreads();

        bf16x8 ah[2], bh[4];
#pragma unroll
        for (int mi = 0; mi < 2; ++mi)
            ah[mi] = *reinterpret_cast<const bf16x8*>(&AH[wm * 32 + mi * 16 + l15][l4 * 8]);
#pragma unroll
        for (int nj = 0; nj < 4; ++nj)
            bh[nj] = *reinterpret_cast<const bf16x8*>(&BH[wn * 64 + nj * 16 + l15][l4 * 8]);
#pragma unroll
        for (int mi = 0; mi < 2; ++mi)
#pragma unroll
            for (int nj = 0; nj < 4; ++nj)
                acc[mi][nj] = __builtin_amdgcn_mfma_f32_16x16x32_bf16(ah[mi], bh[nj], acc[mi][nj], 0, 0, 0);
        __syncthreads();
    }

#pragma unroll
    for (int nj = 0; nj < 4; ++nj) {
        int col = n0 + wn * 64 + nj * 16 + l15;
        float bv_ = bias[col];
#pragma unroll
        for (int mi = 0; mi < 2; ++mi) {
#pragma unroll
            for (int r = 0; r < 4; ++r) {
                int row = m0 + wm * 32 + mi * 16 + l4 * 4 + r;
                float c = acc[mi][nj][r] + bv_;
                if (z == 2) {
                    int hh = col >> 6, d = col & 63, bb = row >> 11, n = row & 2047;
                    Vt[((size_t)((bb * H_ + hh) * D_ + d)) * NSEQ + n] = f2b(c);
                } else {
                    unsigned short* outb = (z == 0) ? Qb : Kb;
                    outb[(size_t)row * 512 + col] = f2b(c * scale);
                }
            }
        }
    }
}

// ---------------- output GEMM with fused set-norm on A (plain bf16) ----------------
__global__ __launch_bounds__(256) void gemm_out_fused_k(const float* __restrict__ xin,
                                                        const float2* __restrict__ partials,
                                                        const float* __restrict__ gamma,
                                                        const float* __restrict__ beta,
                                                        const unsigned short* __restrict__ Whi,
                                                        const float* __restrict__ bo,
                                                        float* __restrict__ outf)
{
    __shared__ unsigned short AH[64][40];
    __shared__ unsigned short BH[128][40];
    __shared__ float rs[256], rss[256];
    __shared__ float2 stt;
    const int tid = threadIdx.x;
    const int w = tid >> 6, lane = tid & 63, l15 = lane & 15, l4 = lane >> 4;
    const int wm = w >> 1, wn = w & 1;
    const int m0 = blockIdx.x * 64, n0 = blockIdx.y * 128;
    const int b = m0 >> 11;

    float2 pp = partials[b * NBLK_RED + tid];
    rs[tid] = pp.x; rss[tid] = pp.y;
    __syncthreads();
    for (int off = 128; off > 0; off >>= 1) {
        if (tid < off) { rs[tid] += rs[tid + off]; rss[tid] += rss[tid + off]; }
        __syncthreads();
    }
    if (tid == 0) {
        float mu  = rs[0] / (float)NFULL;
        float var = rss[0] / (float)NFULL - mu * mu;
        stt = make_float2(mu, rsqrtf(var + EPS_));
    }
    __syncthreads();
    const float2 st = stt;

    f32x4 acc[2][4];
#pragma unroll
    for (int mi = 0; mi < 2; ++mi)
#pragma unroll
        for (int nj = 0; nj < 4; ++nj) acc[mi][nj] = (f32x4){0.f, 0.f, 0.f, 0.f};

    for (int kt = 0; kt < 512; kt += 32) {
#pragma unroll
        for (int p = 0; p < 2; ++p) {
            int f = tid + p * 256;
            int r = f >> 3, c4 = (f & 7) * 4;
            float4 v = *reinterpret_cast<const float4*>(xin + (size_t)(m0 + r) * 512 + kt + c4);
            float4 g  = *reinterpret_cast<const float4*>(gamma + kt + c4);
            float4 be = *reinterpret_cast<const float4*>(beta + kt + c4);
            ushort4 hi;
            hi.x = f2b((v.x - st.x) * st.y * g.x + be.x);
            hi.y = f2b((v.y - st.x) * st.y * g.y + be.y);
            hi.z = f2b((v.z - st.x) * st.y * g.z + be.z);
            hi.w = f2b((v.w - st.x) * st.y * g.w + be.w);
            *reinterpret_cast<ushort4*>(&AH[r][c4]) = hi;
        }
#pragma unroll
        for (int p = 0; p < 2; ++p) {
            int f = tid + p * 256;
            int r = f >> 2, c8 = (f & 3) * 8;
            *reinterpret_cast<uint4*>(&BH[r][c8]) =
                *reinterpret_cast<const uint4*>(Whi + (size_t)(n0 + r) * 512 + kt + c8);
        }
        __syncthreads();

        bf16x8 ah[2], bh[4];
#pragma unroll
        for (int mi = 0; mi < 2; ++mi)
            ah[mi] = *reinterpret_cast<const bf16x8*>(&AH[wm * 32 + mi * 16 + l15][l4 * 8]);
#pragma unroll
        for (int nj = 0; nj < 4; ++nj)
            bh[nj] = *reinterpret_cast<const bf16x8*>(&BH[wn * 64 + nj * 16 + l15][l4 * 8]);
#pragma unroll
        for (int mi = 0; mi < 2; ++mi)
#pragma unroll
            for (int nj = 0; nj < 4; ++nj)
                acc[mi][nj] = __builtin_amdgcn_mfma_f32_16x16x32_bf16(ah[mi], bh[nj], acc[mi][nj], 0, 0, 0);
        __syncthreads();
    }

#pragma unroll
    for (int nj = 0; nj < 4; ++nj) {
        int col = n0 + wn * 64 + nj * 16 + l15;
        float bv = bo[col];
#pragma unroll
        for (int mi = 0; mi < 2; ++mi) {
#pragma unroll
            for (int r = 0; r < 4; ++r) {
                int row = m0 + wm * 32 + mi * 16 + l4 * 4 + r;
                size_t off = (size_t)row * 512 + col;
                float c = acc[mi][nj][r] + bv;
                outf[off] = xin[off] + fmaxf(c, 0.f);
            }
        }
    }
}

// ---------------- MFMA flash attention: 4 waves/block, KV-split x2, dbuf LDS via DMA ----------------
// Continuation of the staging-amortization trend: each block now covers 1024 keys (16 chunks),
// halving split-partial traffic. Wave 0 DMAs K, wave 1 DMAs V. grid (NSEQ/256, H, B*2).
__global__ __launch_bounds__(256, 2) void attn11_k(const unsigned short* __restrict__ Qb,
                                                   const unsigned short* __restrict__ Kb,
                                                   const unsigned short* __restrict__ Vt,
                                                   unsigned short* __restrict__ accS0,
                                                   unsigned short* __restrict__ accS1,
                                                   float* __restrict__ lP)
{
    __shared__ uint4 LDSu[2][1024];     // 2 x 16KB: [K 8KB | V 8KB], swizzled rows of 128B

    const int tid = threadIdx.x;
    const int w = tid >> 6, lane = tid & 63;
    const int l31 = lane & 31, hi = lane >> 5;
    const int h = blockIdx.y;
    const int b = blockIdx.z >> 1, split = blockIdx.z & 1;
    const int qrow0 = blockIdx.x * 256 + w * 64;
    const int kv0 = split * 1024;

    bf16x8 qf[2][4];
#pragma unroll
    for (int qg = 0; qg < 2; ++qg)
#pragma unroll
        for (int ds = 0; ds < 4; ++ds)
            qf[qg][ds] = *reinterpret_cast<const bf16x8*>(
                Qb + ((size_t)(b * NSEQ + qrow0 + qg * 32 + l31)) * C_ + h * D_ + ds * 16 + hi * 8);

    f32x16 acc[2][2];
#pragma unroll
    for (int qg = 0; qg < 2; ++qg)
#pragma unroll
        for (int dh = 0; dh < 2; ++dh)
#pragma unroll
            for (int rg = 0; rg < 16; ++rg) acc[qg][dh][rg] = 0.f;
    float lsum[2] = {0.f, 0.f};

    const unsigned short* Kg = Kb + ((size_t)(b * NSEQ + kv0)) * C_ + h * D_;
    const unsigned short* Vg = Vt + ((size_t)((b * H_ + h) * D_)) * NSEQ + kv0;
    const int r8l = lane >> 3;
    const int scol = ((lane & 7) ^ (r8l & 7)) * 8;   // pre-swizzled global column (elems)

    auto DMA = [&](int buf, int ch) {
        char* base = (char*)LDSu[buf];
        if (w == 0) {
#pragma unroll
            for (int it = 0; it < 8; ++it) {
                const unsigned short* g = Kg + (size_t)(ch + it * 8 + r8l) * C_ + scol;
                __builtin_amdgcn_global_load_lds(
                    (const __attribute__((address_space(1))) unsigned int*)g,
                    (__attribute__((address_space(3))) unsigned int*)(base + it * 1024),
                    16, 0, 0);
            }
        } else if (w == 1) {
            char* vb = base + 8192;
#pragma unroll
            for (int it = 0; it < 8; ++it) {
                const unsigned short* g = Vg + (size_t)(it * 8 + r8l) * NSEQ + ch + scol;
                __builtin_amdgcn_global_load_lds(
                    (const __attribute__((address_space(1))) unsigned int*)g,
                    (__attribute__((address_space(3))) unsigned int*)(vb + it * 1024),
                    16, 0, 0);
            }
        }
    };

    DMA(0, 0);
    __syncthreads();

    for (int c8 = 0; c8 < 16; ++c8) {
        if (c8 + 1 < 16) DMA((c8 + 1) & 1, (c8 + 1) * 64);

        char* Ks = (char*)LDSu[c8 & 1];
        char* Vs = Ks + 8192;
#pragma unroll
        for (int kg = 0; kg < 2; ++kg) {
            bf16x8 kf[4];
#pragma unroll
            for (int ds = 0; ds < 4; ++ds) {
                int row = kg * 32 + l31;
                kf[ds] = *reinterpret_cast<const bf16x8*>(
                    Ks + row * 128 + ((ds * 32 + hi * 16) ^ ((row & 7) << 4)));
            }
            bf16x8 vf[2][2];
#pragma unroll
            for (int dh = 0; dh < 2; ++dh)
#pragma unroll
                for (int st = 0; st < 2; ++st) {
                    int row = dh * 32 + l31;
                    int ks = kg * 2 + st;
                    vf[dh][st] = *reinterpret_cast<const bf16x8*>(
                        Vs + row * 128 + ((ks * 32 + hi * 16) ^ ((row & 7) << 4)));
                }
#pragma unroll
            for (int qg = 0; qg < 2; ++qg) {
                f32x16 S;
#pragma unroll
                for (int rg = 0; rg < 16; ++rg) S[rg] = 0.f;
#pragma unroll
                for (int ds = 0; ds < 4; ++ds)
                    S = __builtin_amdgcn_mfma_f32_32x32x16_bf16(kf[ds], qf[qg][ds], S, 0, 0, 0);

                float p[16];
#pragma unroll
                for (int rg = 0; rg < 16; ++rg) p[rg] = exp2f(S[rg]);
                float ls = ((p[0] + p[1]) + (p[2] + p[3])) + ((p[4] + p[5]) + (p[6] + p[7]))
                         + ((p[8] + p[9]) + (p[10] + p[11])) + ((p[12] + p[13]) + (p[14] + p[15]));
                lsum[qg] += ls;

                unsigned pk[8];
#pragma unroll
                for (int kk = 0; kk < 8; ++kk)
                    asm("v_cvt_pk_bf16_f32 %0, %1, %2" : "=v"(pk[kk]) : "v"(p[2 * kk]), "v"(p[2 * kk + 1]));
                asm("v_permlane32_swap_b32 %0, %1" : "+v"(pk[0]), "+v"(pk[2]));
                asm("v_permlane32_swap_b32 %0, %1" : "+v"(pk[1]), "+v"(pk[3]));
                asm("v_permlane32_swap_b32 %0, %1" : "+v"(pk[4]), "+v"(pk[6]));
                asm("v_permlane32_swap_b32 %0, %1" : "+v"(pk[5]), "+v"(pk[7]));
                bf16x8 pa0 = __builtin_bit_cast(bf16x8, (u32x4){pk[0], pk[1], pk[2], pk[3]});
                bf16x8 pa1 = __builtin_bit_cast(bf16x8, (u32x4){pk[4], pk[5], pk[6], pk[7]});

#pragma unroll
                for (int dh = 0; dh < 2; ++dh) {
                    acc[qg][dh] = __builtin_amdgcn_mfma_f32_32x32x16_bf16(pa0, vf[dh][0], acc[qg][dh], 0, 0, 0);
                    acc[qg][dh] = __builtin_amdgcn_mfma_f32_32x32x16_bf16(pa1, vf[dh][1], acc[qg][dh], 0, 0, 0);
                }
            }
        }
        __syncthreads();   // drains in-flight DMA (vmcnt) + barrier
    }

#pragma unroll
    for (int qg = 0; qg < 2; ++qg) lsum[qg] += __shfl_xor(lsum[qg], 32);

    unsigned short* accOut = (split == 0) ? accS0 : accS1;
    float* lOut = lP + (size_t)split * (B_ * H_ * NSEQ);
#pragma unroll
    for (int qg = 0; qg < 2; ++qg) {
#pragma unroll
        for (int dh = 0; dh < 2; ++dh)
#pragma unroll
            for (int rg = 0; rg < 16; ++rg) {
                int q = qrow0 + qg * 32 + (rg & 3) + 8 * (rg >> 2) + 4 * hi;
                accOut[((size_t)(b * NSEQ + q)) * C_ + h * D_ + dh * 32 + l31] = f2b(acc[qg][dh][rg]);
            }
        if (lane < 32)
            lOut[(size_t)(b * H_ + h) * NSEQ + qrow0 + qg * 32 + lane] = lsum[qg];
    }
}

// ---------------- merge 2 bf16 splits + residual + out-norm partial stats ----------------
__global__ __launch_bounds__(256) void merge2_k(const unsigned short* __restrict__ a0,
                                                const unsigned short* __restrict__ a1,
                                                const float* __restrict__ lP,
                                                const float* __restrict__ query,
                                                float* __restrict__ out_pre,
                                                float2* __restrict__ partials)
{
    int b = blockIdx.y;
    const int LS = B_ * H_ * NSEQ;
    float s = 0.f, ss = 0.f;
#pragma unroll
    for (int i = 0; i < 4; ++i) {
        int pos = blockIdx.x * 1024 + threadIdx.x + i * 256;
        size_t i4 = (size_t)b * N4 + pos;
        int n = pos >> 7;
        int hh = (pos & 127) >> 4;
        size_t li = (size_t)(b * H_ + hh) * NSEQ + n;
        float inv = 1.0f / (lP[li] + lP[LS + li]);
        ushort4 u0 = reinterpret_cast<const ushort4*>(a0)[i4];
        ushort4 u1 = reinterpret_cast<const ushort4*>(a1)[i4];
        float4 q4 = reinterpret_cast<const float4*>(query)[i4];
        float4 r;
        r.x = q4.x + (b2f(u0.x) + b2f(u1.x)) * inv;
        r.y = q4.y + (b2f(u0.y) + b2f(u1.y)) * inv;
        r.z = q4.z + (b2f(u0.z) + b2f(u1.z)) * inv;
        r.w = q4.w + (b2f(u0.w) + b2f(u1.w)) * inv;
        reinterpret_cast<float4*>(out_pre)[i4] = r;
        s  += (r.x + r.y) + (r.z + r.w);
        ss += (r.x * r.x + r.y * r.y) + (r.z * r.z + r.w * r.w);
    }
    __shared__ float rs[256], rss[256];
    rs[threadIdx.x] = s; rss[threadIdx.x] = ss;
    __syncthreads();
    for (int off = 128; off > 0; off >>= 1) {
        if (threadIdx.x < off) {
            rs[threadIdx.x]  += rs[threadIdx.x + off];
            rss[threadIdx.x] += rss[threadIdx.x + off];
        }
        __syncthreads();
    }
    if (threadIdx.x == 0)
        partials[b * NBLK_RED + blockIdx.x] = make_float2(rs[0], rss[0]);
}

// ---------------- launcher ----------------
extern "C" void kernel_launch(void* const* d_in, const int* in_sizes, int n_in,
                              void* d_out, int out_size, void* d_ws, size_t ws_size,
                              hipStream_t stream)
{
    const float* query     = (const float*)d_in[0];
    const float* key_value = (const float*)d_in[1];
    const float* Wq = (const float*)d_in[2];
    const float* bq = (const float*)d_in[3];
    const float* Wk = (const float*)d_in[4];
    const float* bk = (const float*)d_in[5];
    const float* Wv = (const float*)d_in[6];
    const float* bv = (const float*)d_in[7];
    const float* Wo = (const float*)d_in[8];
    const float* bo = (const float*)d_in[9];
    const float* g_q = (const float*)d_in[10];
    const float* be_q = (const float*)d_in[11];
    const float* g_k = (const float*)d_in[12];
    const float* be_k = (const float*)d_in[13];
    const float* g_o = (const float*)d_in[14];
    const float* be_o = (const float*)d_in[15];
    float* out = (float*)d_out;

    float* ws = (float*)d_ws;
    float2* part_q  = (float2*)ws;                       // 512 f2
    float2* part_kv = part_q + 2 * NBLK_RED;             // 512 f2
    float2* part_o  = part_kv + 2 * NBLK_RED;            // 512 f2

    const size_t SZ = (size_t)B_ * NFULL;                // 2,097,152 elements
    char* p = (char*)(ws + 16384);
    unsigned short* accS0  = (unsigned short*)p; p += SZ * 2;   // bf16 partials (4MB each)
    unsigned short* accS1  = (unsigned short*)p; p += SZ * 2;
    unsigned short* Wt_hi  = (unsigned short*)p; p += (size_t)4 * 512 * 512 * 2;
    unsigned short* Qb     = (unsigned short*)p; p += SZ * 2;
    unsigned short* Kb     = (unsigned short*)p; p += SZ * 2;
    unsigned short* Vt     = (unsigned short*)p; p += SZ * 2;
    float*          out_pre = (float*)p;         p += SZ * 4;
    float*          lP     = (float*)p;          p += (size_t)2 * B_ * H_ * NSEQ * 4;

    dim3 blk(256);

    setup_k<<<dim3(1280), blk, 0, stream>>>(query, key_value, Wq, Wk, Wv, Wo,
                                            Wt_hi, part_q, part_kv);

    gemm3_fused_k<<<dim3(64, 4, 3), blk, 0, stream>>>(query, key_value, part_q, part_kv,
                                                      g_q, be_q, g_k, be_k,
                                                      Wt_hi, bq, bk, bv, Qb, Kb, Vt);

    attn11_k<<<dim3(NSEQ / 256, H_, B_ * 2), dim3(256), 0, stream>>>(Qb, Kb, Vt,
                                                                     accS0, accS1, lP);

    merge2_k<<<dim3(NBLK_RED, B_), blk, 0, stream>>>(accS0, accS1, lP,
                                                     query, out_pre, part_o);

    gemm_out_fused_k<<<dim3(64, 4), blk, 0, stream>>>(out_pre, part_o, g_o, be_o,
                                                      Wt_hi + (size_t)3 * 512 * 512,
                                                      bo, out);
}

// Round 24
// 81.935 us; speedup vs baseline: 1.0178x; 1.0178x over previous
//
#include <hip/hip_runtime.h>
#include <cstddef>
#include <cstdint>

// ---------------- problem constants ----------------
#define B_     2
#define NSEQ   2048
#define C_     512
#define H_     8
#define D_     64
#define NFULL  (NSEQ * C_)        // 1048576 elems per batch
#define N4     (NFULL / 4)        // 262144 float4 per batch
#define EPS_   1e-5f
#define LOG2E  1.4426950408889634f
#define RSQRT512 0.044194173824159216f
#define ASCL   (RSQRT512 * LOG2E)
#define NBLK_RED 256

typedef __attribute__((ext_vector_type(8)))  short bf16x8;
typedef __attribute__((ext_vector_type(4)))  float f32x4;
typedef __attribute__((ext_vector_type(16))) float f32x16;
typedef __attribute__((ext_vector_type(4)))  unsigned int u32x4;

__device__ __forceinline__ unsigned short f2b(float x) {
    unsigned int u = __float_as_uint(x);
    u += 0x7FFFu + ((u >> 16) & 1u);          // RNE
    return (unsigned short)(u >> 16);
}
__device__ __forceinline__ float b2f(unsigned short h) {
    return __uint_as_float(((unsigned int)h) << 16);
}

// ---------------- setup: weight prep (blocks 0..255) + set-norm partial stats (256..1279) ----------------
__global__ __launch_bounds__(256) void setup_k(const float* __restrict__ query,
                                               const float* __restrict__ key_value,
                                               const float* __restrict__ Wq, const float* __restrict__ Wk,
                                               const float* __restrict__ Wv, const float* __restrict__ Wo,
                                               unsigned short* __restrict__ Wt_hi,
                                               float2* __restrict__ part_q,
                                               float2* __restrict__ part_kv)
{
    __shared__ float T[64][65];
    __shared__ float rs[256], rss[256];
    const int bid = blockIdx.x;
    const int tid = threadIdx.x;

    if (bid < 256) {
        int z = bid >> 6;
        const float* W = (z == 0) ? Wq : (z == 1) ? Wk : (z == 2) ? Wv : Wo;
        int k0 = (bid & 7) * 64, n0 = ((bid >> 3) & 7) * 64;
#pragma unroll
        for (int i = 0; i < 4; ++i) {
            int idx = tid + i * 256;
            int r = idx >> 4, c4 = (idx & 15) * 4;
            float4 v = *reinterpret_cast<const float4*>(W + (size_t)(k0 + r) * 512 + n0 + c4);
            T[r][c4] = v.x; T[r][c4 + 1] = v.y; T[r][c4 + 2] = v.z; T[r][c4 + 3] = v.w;
        }
        __syncthreads();
#pragma unroll
        for (int i = 0; i < 4; ++i) {
            int idx = tid + i * 256;
            int n = idx >> 4, k4 = (idx & 15) * 4;
            ushort4 hi;
            hi.x = f2b(T[k4 + 0][n]); hi.y = f2b(T[k4 + 1][n]);
            hi.z = f2b(T[k4 + 2][n]); hi.w = f2b(T[k4 + 3][n]);
            size_t o = ((size_t)z * 512 + n0 + n) * 512 + k0 + k4;
            *reinterpret_cast<ushort4*>(Wt_hi + o) = hi;
        }
    } else {
        int r = bid - 256;
        int zz = r >> 9, bb = (r >> 8) & 1, xx = r & 255;
        const float* x = zz ? key_value : query;
        float2* partials = zz ? part_kv : part_q;
        const float4* xb = reinterpret_cast<const float4*>(x + (size_t)bb * NFULL);
        int base = xx * 1024 + tid;
        float s = 0.f, ss = 0.f;
#pragma unroll
        for (int i = 0; i < 4; ++i) {
            float4 v = xb[base + i * 256];
            s  += (v.x + v.y) + (v.z + v.w);
            ss += (v.x * v.x + v.y * v.y) + (v.z * v.z + v.w * v.w);
        }
        rs[tid] = s; rss[tid] = ss;
        __syncthreads();
        for (int off = 128; off > 0; off >>= 1) {
            if (tid < off) { rs[tid] += rs[tid + off]; rss[tid] += rss[tid + off]; }
            __syncthreads();
        }
        if (tid == 0)
            partials[bb * NBLK_RED + xx] = make_float2(rs[0], rss[0]);
    }
}

// ---------------- QKV projection GEMM with fused set-norm on A (reads fp32 inputs) ----------------
__global__ __launch_bounds__(256) void gemm3_fused_k(const float* __restrict__ query,
                                                     const float* __restrict__ key_value,
                                                     const float2* __restrict__ part_q,
                                                     const float2* __restrict__ part_kv,
                                                     const float* __restrict__ g_q, const float* __restrict__ be_q,
                                                     const float* __restrict__ g_k, const float* __restrict__ be_k,
                                                     const unsigned short* __restrict__ Wt_hi,
                                                     const float* __restrict__ bq, const float* __restrict__ bk,
                                                     const float* __restrict__ bv,
                                                     unsigned short* __restrict__ Qb,
                                                     unsigned short* __restrict__ Kb,
                                                     unsigned short* __restrict__ Vt)
{
    int z = blockIdx.z;
    const float* xin = (z == 0) ? query : key_value;
    const float2* partials = (z == 0) ? part_q : part_kv;
    const float* gamma = (z == 0) ? g_q : g_k;
    const float* beta  = (z == 0) ? be_q : be_k;
    const unsigned short* W = Wt_hi + (size_t)z * 512 * 512;
    const float* bias = (z == 0) ? bq : (z == 1) ? bk : bv;
    float scale = (z == 0) ? (float)ASCL : 1.0f;

    __shared__ unsigned short AH[64][40];
    __shared__ unsigned short BH[128][40];
    __shared__ float rs[256], rss[256];
    __shared__ float2 stt;
    const int tid = threadIdx.x;
    const int w = tid >> 6, lane = tid & 63, l15 = lane & 15, l4 = lane >> 4;
    const int wm = w >> 1, wn = w & 1;
    const int m0 = blockIdx.x * 64, n0 = blockIdx.y * 128;
    const int b = m0 >> 11;

    float2 pp = partials[b * NBLK_RED + tid];
    rs[tid] = pp.x; rss[tid] = pp.y;
    __syncthreads();
    for (int off = 128; off > 0; off >>= 1) {
        if (tid < off) { rs[tid] += rs[tid + off]; rss[tid] += rss[tid + off]; }
        __syncthreads();
    }
    if (tid == 0) {
        float mu  = rs[0] / (float)NFULL;
        float var = rss[0] / (float)NFULL - mu * mu;
        stt = make_float2(mu, rsqrtf(var + EPS_));
    }
    __syncthreads();
    const float2 st = stt;

    f32x4 acc[2][4];
#pragma unroll
    for (int mi = 0; mi < 2; ++mi)
#pragma unroll
        for (int nj = 0; nj < 4; ++nj) acc[mi][nj] = (f32x4){0.f, 0.f, 0.f, 0.f};

    for (int kt = 0; kt < 512; kt += 32) {
#pragma unroll
        for (int p = 0; p < 2; ++p) {   // A tile 64x32 fp32, normalize -> bf16 LDS
            int f = tid + p * 256;
            int r = f >> 3, c4 = (f & 7) * 4;
            float4 v = *reinterpret_cast<const float4*>(xin + (size_t)(m0 + r) * 512 + kt + c4);
            float4 g  = *reinterpret_cast<const float4*>(gamma + kt + c4);
            float4 be = *reinterpret_cast<const float4*>(beta + kt + c4);
            ushort4 hi;
            hi.x = f2b((v.x - st.x) * st.y * g.x + be.x);
            hi.y = f2b((v.y - st.x) * st.y * g.y + be.y);
            hi.z = f2b((v.z - st.x) * st.y * g.z + be.z);
            hi.w = f2b((v.w - st.x) * st.y * g.w + be.w);
            *reinterpret_cast<ushort4*>(&AH[r][c4]) = hi;
        }
#pragma unroll
        for (int p = 0; p < 2; ++p) {   // B tile 128x32 = 512 uint4, 2/thread
            int f = tid + p * 256;
            int r = f >> 2, c8 = (f & 3) * 8;
            *reinterpret_cast<uint4*>(&BH[r][c8]) =
                *reinterpret_cast<const uint4*>(W + (size_t)(n0 + r) * 512 + kt + c8);
        }
        __syncthreads();

        bf16x8 ah[2], bh[4];
#pragma unroll
        for (int mi = 0; mi < 2; ++mi)
            ah[mi] = *reinterpret_cast<const bf16x8*>(&AH[wm * 32 + mi * 16 + l15][l4 * 8]);
#pragma unroll
        for (int nj = 0; nj < 4; ++nj)
            bh[nj] = *reinterpret_cast<const bf16x8*>(&BH[wn * 64 + nj * 16 + l15][l4 * 8]);
#pragma unroll
        for (int mi = 0; mi < 2; ++mi)
#pragma unroll
            for (int nj = 0; nj < 4; ++nj)
                acc[mi][nj] = __builtin_amdgcn_mfma_f32_16x16x32_bf16(ah[mi], bh[nj], acc[mi][nj], 0, 0, 0);
        __syncthreads();
    }

#pragma unroll
    for (int nj = 0; nj < 4; ++nj) {
        int col = n0 + wn * 64 + nj * 16 + l15;
        float bv_ = bias[col];
#pragma unroll
        for (int mi = 0; mi < 2; ++mi) {
#pragma unroll
            for (int r = 0; r < 4; ++r) {
                int row = m0 + wm * 32 + mi * 16 + l4 * 4 + r;
                float c = acc[mi][nj][r] + bv_;
                if (z == 2) {
                    int hh = col >> 6, d = col & 63, bb = row >> 11, n = row & 2047;
                    Vt[((size_t)((bb * H_ + hh) * D_ + d)) * NSEQ + n] = f2b(c);
                } else {
                    unsigned short* outb = (z == 0) ? Qb : Kb;
                    outb[(size_t)row * 512 + col] = f2b(c * scale);
                }
            }
        }
    }
}

// ---------------- output GEMM with fused set-norm on A (plain bf16) ----------------
__global__ __launch_bounds__(256) void gemm_out_fused_k(const float* __restrict__ xin,
                                                        const float2* __restrict__ partials,
                                                        const float* __restrict__ gamma,
                                                        const float* __restrict__ beta,
                                                        const unsigned short* __restrict__ Whi,
                                                        const float* __restrict__ bo,
                                                        float* __restrict__ outf)
{
    __shared__ unsigned short AH[64][40];
    __shared__ unsigned short BH[128][40];
    __shared__ float rs[256], rss[256];
    __shared__ float2 stt;
    const int tid = threadIdx.x;
    const int w = tid >> 6, lane = tid & 63, l15 = lane & 15, l4 = lane >> 4;
    const int wm = w >> 1, wn = w & 1;
    const int m0 = blockIdx.x * 64, n0 = blockIdx.y * 128;
    const int b = m0 >> 11;

    float2 pp = partials[b * NBLK_RED + tid];
    rs[tid] = pp.x; rss[tid] = pp.y;
    __syncthreads();
    for (int off = 128; off > 0; off >>= 1) {
        if (tid < off) { rs[tid] += rs[tid + off]; rss[tid] += rss[tid + off]; }
        __syncthreads();
    }
    if (tid == 0) {
        float mu  = rs[0] / (float)NFULL;
        float var = rss[0] / (float)NFULL - mu * mu;
        stt = make_float2(mu, rsqrtf(var + EPS_));
    }
    __syncthreads();
    const float2 st = stt;

    f32x4 acc[2][4];
#pragma unroll
    for (int mi = 0; mi < 2; ++mi)
#pragma unroll
        for (int nj = 0; nj < 4; ++nj) acc[mi][nj] = (f32x4){0.f, 0.f, 0.f, 0.f};

    for (int kt = 0; kt < 512; kt += 32) {
#pragma unroll
        for (int p = 0; p < 2; ++p) {
            int f = tid + p * 256;
            int r = f >> 3, c4 = (f & 7) * 4;
            float4 v = *reinterpret_cast<const float4*>(xin + (size_t)(m0 + r) * 512 + kt + c4);
            float4 g  = *reinterpret_cast<const float4*>(gamma + kt + c4);
            float4 be = *reinterpret_cast<const float4*>(beta + kt + c4);
            ushort4 hi;
            hi.x = f2b((v.x - st.x) * st.y * g.x + be.x);
            hi.y = f2b((v.y - st.x) * st.y * g.y + be.y);
            hi.z = f2b((v.z - st.x) * st.y * g.z + be.z);
            hi.w = f2b((v.w - st.x) * st.y * g.w + be.w);
            *reinterpret_cast<ushort4*>(&AH[r][c4]) = hi;
        }
#pragma unroll
        for (int p = 0; p < 2; ++p) {
            int f = tid + p * 256;
            int r = f >> 2, c8 = (f & 3) * 8;
            *reinterpret_cast<uint4*>(&BH[r][c8]) =
                *reinterpret_cast<const uint4*>(Whi + (size_t)(n0 + r) * 512 + kt + c8);
        }
        __syncthreads();

        bf16x8 ah[2], bh[4];
#pragma unroll
        for (int mi = 0; mi < 2; ++mi)
            ah[mi] = *reinterpret_cast<const bf16x8*>(&AH[wm * 32 + mi * 16 + l15][l4 * 8]);
#pragma unroll
        for (int nj = 0; nj < 4; ++nj)
            bh[nj] = *reinterpret_cast<const bf16x8*>(&BH[wn * 64 + nj * 16 + l15][l4 * 8]);
#pragma unroll
        for (int mi = 0; mi < 2; ++mi)
#pragma unroll
            for (int nj = 0; nj < 4; ++nj)
                acc[mi][nj] = __builtin_amdgcn_mfma_f32_16x16x32_bf16(ah[mi], bh[nj], acc[mi][nj], 0, 0, 0);
        __syncthreads();
    }

#pragma unroll
    for (int nj = 0; nj < 4; ++nj) {
        int col = n0 + wn * 64 + nj * 16 + l15;
        float bv = bo[col];
#pragma unroll
        for (int mi = 0; mi < 2; ++mi) {
#pragma unroll
            for (int r = 0; r < 4; ++r) {
                int row = m0 + wm * 32 + mi * 16 + l4 * 4 + r;
                size_t off = (size_t)row * 512 + col;
                float c = acc[mi][nj][r] + bv;
                outf[off] = xin[off] + fmaxf(c, 0.f);
            }
        }
    }
}

// ---------------- MFMA flash attention: 4 waves/block, 256 q-rows/block, dbuf LDS via DMA ----------------
// Round-22 best-known config (82.1us): split x4, 512 blocks (2 blocks/CU).
// Wave 0 DMAs K, wave 1 DMAs V, waves 2-3 skip. grid (NSEQ/256, H, B*4).
__global__ __launch_bounds__(256, 2) void attn10_k(const unsigned short* __restrict__ Qb,
                                                   const unsigned short* __restrict__ Kb,
                                                   const unsigned short* __restrict__ Vt,
                                                   unsigned short* __restrict__ accS0, unsigned short* __restrict__ accS1,
                                                   unsigned short* __restrict__ accS2, unsigned short* __restrict__ accS3,
                                                   float* __restrict__ lP)
{
    __shared__ uint4 LDSu[2][1024];     // 2 x 16KB: [K 8KB | V 8KB], swizzled rows of 128B

    const int tid = threadIdx.x;
    const int w = tid >> 6, lane = tid & 63;
    const int l31 = lane & 31, hi = lane >> 5;
    const int h = blockIdx.y;
    const int b = blockIdx.z >> 2, split = blockIdx.z & 3;
    const int qrow0 = blockIdx.x * 256 + w * 64;
    const int kv0 = split * 512;

    bf16x8 qf[2][4];
#pragma unroll
    for (int qg = 0; qg < 2; ++qg)
#pragma unroll
        for (int ds = 0; ds < 4; ++ds)
            qf[qg][ds] = *reinterpret_cast<const bf16x8*>(
                Qb + ((size_t)(b * NSEQ + qrow0 + qg * 32 + l31)) * C_ + h * D_ + ds * 16 + hi * 8);

    f32x16 acc[2][2];
#pragma unroll
    for (int qg = 0; qg < 2; ++qg)
#pragma unroll
        for (int dh = 0; dh < 2; ++dh)
#pragma unroll
            for (int rg = 0; rg < 16; ++rg) acc[qg][dh][rg] = 0.f;
    float lsum[2] = {0.f, 0.f};

    const unsigned short* Kg = Kb + ((size_t)(b * NSEQ + kv0)) * C_ + h * D_;
    const unsigned short* Vg = Vt + ((size_t)((b * H_ + h) * D_)) * NSEQ + kv0;
    const int r8l = lane >> 3;
    const int scol = ((lane & 7) ^ (r8l & 7)) * 8;   // pre-swizzled global column (elems)

    auto DMA = [&](int buf, int ch) {
        char* base = (char*)LDSu[buf];
        if (w == 0) {
#pragma unroll
            for (int it = 0; it < 8; ++it) {
                const unsigned short* g = Kg + (size_t)(ch + it * 8 + r8l) * C_ + scol;
                __builtin_amdgcn_global_load_lds(
                    (const __attribute__((address_space(1))) unsigned int*)g,
                    (__attribute__((address_space(3))) unsigned int*)(base + it * 1024),
                    16, 0, 0);
            }
        } else if (w == 1) {
            char* vb = base + 8192;
#pragma unroll
            for (int it = 0; it < 8; ++it) {
                const unsigned short* g = Vg + (size_t)(it * 8 + r8l) * NSEQ + ch + scol;
                __builtin_amdgcn_global_load_lds(
                    (const __attribute__((address_space(1))) unsigned int*)g,
                    (__attribute__((address_space(3))) unsigned int*)(vb + it * 1024),
                    16, 0, 0);
            }
        }
    };

    DMA(0, 0);
    __syncthreads();

    for (int c8 = 0; c8 < 8; ++c8) {
        if (c8 + 1 < 8) DMA((c8 + 1) & 1, (c8 + 1) * 64);

        char* Ks = (char*)LDSu[c8 & 1];
        char* Vs = Ks + 8192;
#pragma unroll
        for (int kg = 0; kg < 2; ++kg) {
            bf16x8 kf[4];
#pragma unroll
            for (int ds = 0; ds < 4; ++ds) {
                int row = kg * 32 + l31;
                kf[ds] = *reinterpret_cast<const bf16x8*>(
                    Ks + row * 128 + ((ds * 32 + hi * 16) ^ ((row & 7) << 4)));
            }
            bf16x8 vf[2][2];
#pragma unroll
            for (int dh = 0; dh < 2; ++dh)
#pragma unroll
                for (int st = 0; st < 2; ++st) {
                    int row = dh * 32 + l31;
                    int ks = kg * 2 + st;
                    vf[dh][st] = *reinterpret_cast<const bf16x8*>(
                        Vs + row * 128 + ((ks * 32 + hi * 16) ^ ((row & 7) << 4)));
                }
#pragma unroll
            for (int qg = 0; qg < 2; ++qg) {
                f32x16 S;
#pragma unroll
                for (int rg = 0; rg < 16; ++rg) S[rg] = 0.f;
#pragma unroll
                for (int ds = 0; ds < 4; ++ds)
                    S = __builtin_amdgcn_mfma_f32_32x32x16_bf16(kf[ds], qf[qg][ds], S, 0, 0, 0);

                float p[16];
#pragma unroll
                for (int rg = 0; rg < 16; ++rg) p[rg] = exp2f(S[rg]);
                float ls = ((p[0] + p[1]) + (p[2] + p[3])) + ((p[4] + p[5]) + (p[6] + p[7]))
                         + ((p[8] + p[9]) + (p[10] + p[11])) + ((p[12] + p[13]) + (p[14] + p[15]));
                lsum[qg] += ls;

                unsigned pk[8];
#pragma unroll
                for (int kk = 0; kk < 8; ++kk)
                    asm("v_cvt_pk_bf16_f32 %0, %1, %2" : "=v"(pk[kk]) : "v"(p[2 * kk]), "v"(p[2 * kk + 1]));
                asm("v_permlane32_swap_b32 %0, %1" : "+v"(pk[0]), "+v"(pk[2]));
                asm("v_permlane32_swap_b32 %0, %1" : "+v"(pk[1]), "+v"(pk[3]));
                asm("v_permlane32_swap_b32 %0, %1" : "+v"(pk[4]), "+v"(pk[6]));
                asm("v_permlane32_swap_b32 %0, %1" : "+v"(pk[5]), "+v"(pk[7]));
                bf16x8 pa0 = __builtin_bit_cast(bf16x8, (u32x4){pk[0], pk[1], pk[2], pk[3]});
                bf16x8 pa1 = __builtin_bit_cast(bf16x8, (u32x4){pk[4], pk[5], pk[6], pk[7]});

#pragma unroll
                for (int dh = 0; dh < 2; ++dh) {
                    acc[qg][dh] = __builtin_amdgcn_mfma_f32_32x32x16_bf16(pa0, vf[dh][0], acc[qg][dh], 0, 0, 0);
                    acc[qg][dh] = __builtin_amdgcn_mfma_f32_32x32x16_bf16(pa1, vf[dh][1], acc[qg][dh], 0, 0, 0);
                }
            }
        }
        __syncthreads();   // drains in-flight DMA (vmcnt) + barrier
    }

#pragma unroll
    for (int qg = 0; qg < 2; ++qg) lsum[qg] += __shfl_xor(lsum[qg], 32);

    unsigned short* accOut = (split == 0) ? accS0 : (split == 1) ? accS1 : (split == 2) ? accS2 : accS3;
    float* lOut = lP + (size_t)split * (B_ * H_ * NSEQ);
#pragma unroll
    for (int qg = 0; qg < 2; ++qg) {
#pragma unroll
        for (int dh = 0; dh < 2; ++dh)
#pragma unroll
            for (int rg = 0; rg < 16; ++rg) {
                int q = qrow0 + qg * 32 + (rg & 3) + 8 * (rg >> 2) + 4 * hi;
                accOut[((size_t)(b * NSEQ + q)) * C_ + h * D_ + dh * 32 + l31] = f2b(acc[qg][dh][rg]);
            }
        if (lane < 32)
            lOut[(size_t)(b * H_ + h) * NSEQ + qrow0 + qg * 32 + lane] = lsum[qg];
    }
}

// ---------------- merge 4 bf16 splits + residual + out-norm partial stats ----------------
__global__ __launch_bounds__(256) void merge4_k(const unsigned short* __restrict__ a0,
                                                const unsigned short* __restrict__ a1,
                                                const unsigned short* __restrict__ a2,
                                                const unsigned short* __restrict__ a3,
                                                const float* __restrict__ lP,
                                                const float* __restrict__ query,
                                                float* __restrict__ out_pre,
                                                float2* __restrict__ partials)
{
    int b = blockIdx.y;
    const int LS = B_ * H_ * NSEQ;
    float s = 0.f, ss = 0.f;
#pragma unroll
    for (int i = 0; i < 4; ++i) {
        int pos = blockIdx.x * 1024 + threadIdx.x + i * 256;
        size_t i4 = (size_t)b * N4 + pos;
        int n = pos >> 7;
        int hh = (pos & 127) >> 4;
        size_t li = (size_t)(b * H_ + hh) * NSEQ + n;
        float inv = 1.0f / (((lP[li] + lP[LS + li]) + (lP[2 * LS + li] + lP[3 * LS + li])));
        ushort4 u0 = reinterpret_cast<const ushort4*>(a0)[i4];
        ushort4 u1 = reinterpret_cast<const ushort4*>(a1)[i4];
        ushort4 u2 = reinterpret_cast<const ushort4*>(a2)[i4];
        ushort4 u3 = reinterpret_cast<const ushort4*>(a3)[i4];
        float4 q4 = reinterpret_cast<const float4*>(query)[i4];
        float4 r;
        r.x = q4.x + ((b2f(u0.x) + b2f(u1.x)) + (b2f(u2.x) + b2f(u3.x))) * inv;
        r.y = q4.y + ((b2f(u0.y) + b2f(u1.y)) + (b2f(u2.y) + b2f(u3.y))) * inv;
        r.z = q4.z + ((b2f(u0.z) + b2f(u1.z)) + (b2f(u2.z) + b2f(u3.z))) * inv;
        r.w = q4.w + ((b2f(u0.w) + b2f(u1.w)) + (b2f(u2.w) + b2f(u3.w))) * inv;
        reinterpret_cast<float4*>(out_pre)[i4] = r;
        s  += (r.x + r.y) + (r.z + r.w);
        ss += (r.x * r.x + r.y * r.y) + (r.z * r.z + r.w * r.w);
    }
    __shared__ float rs[256], rss[256];
    rs[threadIdx.x] = s; rss[threadIdx.x] = ss;
    __syncthreads();
    for (int off = 128; off > 0; off >>= 1) {
        if (threadIdx.x < off) {
            rs[threadIdx.x]  += rs[threadIdx.x + off];
            rss[threadIdx.x] += rss[threadIdx.x + off];
        }
        __syncthreads();
    }
    if (threadIdx.x == 0)
        partials[b * NBLK_RED + blockIdx.x] = make_float2(rs[0], rss[0]);
}

// ---------------- launcher ----------------
extern "C" void kernel_launch(void* const* d_in, const int* in_sizes, int n_in,
                              void* d_out, int out_size, void* d_ws, size_t ws_size,
                              hipStream_t stream)
{
    const float* query     = (const float*)d_in[0];
    const float* key_value = (const float*)d_in[1];
    const float* Wq = (const float*)d_in[2];
    const float* bq = (const float*)d_in[3];
    const float* Wk = (const float*)d_in[4];
    const float* bk = (const float*)d_in[5];
    const float* Wv = (const float*)d_in[6];
    const float* bv = (const float*)d_in[7];
    const float* Wo = (const float*)d_in[8];
    const float* bo = (const float*)d_in[9];
    const float* g_q = (const float*)d_in[10];
    const float* be_q = (const float*)d_in[11];
    const float* g_k = (const float*)d_in[12];
    const float* be_k = (const float*)d_in[13];
    const float* g_o = (const float*)d_in[14];
    const float* be_o = (const float*)d_in[15];
    float* out = (float*)d_out;

    float* ws = (float*)d_ws;
    float2* part_q  = (float2*)ws;                       // 512 f2
    float2* part_kv = part_q + 2 * NBLK_RED;             // 512 f2
    float2* part_o  = part_kv + 2 * NBLK_RED;            // 512 f2

    const size_t SZ = (size_t)B_ * NFULL;                // 2,097,152 elements
    char* p = (char*)(ws + 16384);
    unsigned short* accS0  = (unsigned short*)p; p += SZ * 2;   // bf16 partials (4MB each)
    unsigned short* accS1  = (unsigned short*)p; p += SZ * 2;
    unsigned short* accS2  = (unsigned short*)p; p += SZ * 2;
    unsigned short* accS3  = (unsigned short*)p; p += SZ * 2;
    unsigned short* Wt_hi  = (unsigned short*)p; p += (size_t)4 * 512 * 512 * 2;
    unsigned short* Qb     = (unsigned short*)p; p += SZ * 2;
    unsigned short* Kb     = (unsigned short*)p; p += SZ * 2;
    unsigned short* Vt     = (unsigned short*)p; p += SZ * 2;
    float*          out_pre = (float*)p;         p += SZ * 4;
    float*          lP     = (float*)p;          p += (size_t)4 * B_ * H_ * NSEQ * 4;

    dim3 blk(256);

    setup_k<<<dim3(1280), blk, 0, stream>>>(query, key_value, Wq, Wk, Wv, Wo,
                                            Wt_hi, part_q, part_kv);

    gemm3_fused_k<<<dim3(64, 4, 3), blk, 0, stream>>>(query, key_value, part_q, part_kv,
                                                      g_q, be_q, g_k, be_k,
                                                      Wt_hi, bq, bk, bv, Qb, Kb, Vt);

    attn10_k<<<dim3(NSEQ / 256, H_, B_ * 4), dim3(256), 0, stream>>>(Qb, Kb, Vt,
                                                                     accS0, accS1, accS2, accS3, lP);

    merge4_k<<<dim3(NBLK_RED, B_), blk, 0, stream>>>(accS0, accS1, accS2, accS3, lP,
                                                     query, out_pre, part_o);

    gemm_out_fused_k<<<dim3(64, 4), blk, 0, stream>>>(out_pre, part_o, g_o, be_o,
                                                      Wt_hi + (size_t)3 * 512 * 512,
                                                      bo, out);
}